// Round 18
// baseline (92.307 us; speedup 1.0000x reference)
//
#include <hip/hip_runtime.h>
#include <hip/hip_bf16.h>
#include <hip/hip_fp16.h>
#include <stdint.h>

typedef __hip_bfloat16 bf16;
typedef __attribute__((ext_vector_type(8))) short short8;    // 8 bf16 MFMA A/B frag
typedef __attribute__((ext_vector_type(4))) float f32x4;
typedef __attribute__((ext_vector_type(16))) float f32x16;   // 32x32 MFMA C/D
typedef __attribute__((ext_vector_type(4))) int int4v;
typedef __attribute__((ext_vector_type(4))) unsigned short ushort4v;

#define MFMA16(A,B,C) __builtin_amdgcn_mfma_f32_16x16x32_bf16(A,B,C,0,0,0)
#define MFMA32(A,B,C) __builtin_amdgcn_mfma_f32_32x32x16_bf16(A,B,C,0,0,0)

// async global->LDS, 16B per lane. LDS dest = wave-uniform base + lane*16.
static __device__ __forceinline__ void g2lds16(const void* g, void* l) {
  __builtin_amdgcn_global_load_lds(
      (__attribute__((address_space(1))) void*)(g),
      (__attribute__((address_space(3))) void*)(l), 16, 0, 0);
}

// swizzled chunk index within a [rows][64 bf16] LDS tile (chunks = 8 bf16 = 16B)
static __device__ __forceinline__ int swz8(int row, int kc) {
  return row * 8 + (kc ^ (row & 7));
}

static __device__ __forceinline__ unsigned short f2bf_bits(float f) {
  bf16 t = __float2bfloat16(f); unsigned short u; __builtin_memcpy(&u, &t, 2); return u;
}
static __device__ __forceinline__ unsigned short f2h_bits(float f) {
  __half t = __float2half(f); unsigned short u; __builtin_memcpy(&u, &t, 2); return u;
}

// ---------------- merged preprocessing ----------------
template<bool HALFOUT>
static __device__ __forceinline__ void tileT(const float* __restrict__ in,
                                             unsigned short* __restrict__ out,
                                             int R, int C, int tr, int tc, int tid,
                                             float (*tls)[65]) {
  const int rr0 = tid >> 4, c4 = tid & 15;
  #pragma unroll
  for (int rr = 0; rr < 4; ++rr) {
    int r = rr0 + rr * 16;
    float4 v = *(const float4*)(in + (size_t)(tr * 64 + r) * C + tc * 64 + c4 * 4);
    tls[r][c4 * 4 + 0] = v.x; tls[r][c4 * 4 + 1] = v.y;
    tls[r][c4 * 4 + 2] = v.z; tls[r][c4 * 4 + 3] = v.w;
  }
  __syncthreads();
  #pragma unroll
  for (int rr = 0; rr < 4; ++rr) {
    int r2 = rr0 + rr * 16;
    ushort4v o;
    #pragma unroll
    for (int k = 0; k < 4; ++k) {
      float f = tls[c4 * 4 + k][r2];
      o[k] = HALFOUT ? f2h_bits(f) : f2bf_bits(f);
    }
    *(ushort4v*)(out + (size_t)(tc * 64 + r2) * R + tr * 64 + c4 * 4) = o;
  }
}

__global__ __launch_bounds__(256)
void k_prep(const float* __restrict__ x, bf16* __restrict__ xb,
            const float* __restrict__ wqkv, unsigned short* __restrict__ wqkvT,
            const float* __restrict__ wout, unsigned short* __restrict__ woutT,
            const float* __restrict__ mask, unsigned short* __restrict__ maskT) {
  __shared__ float tls[64][65];
  const int bid = blockIdx.x, tid = threadIdx.x;
  if (bid < 768) {                       // x fp32 -> bf16: 786432 float4s, 4 per thread
    #pragma unroll
    for (int j = 0; j < 4; ++j) {
      int i = bid * 1024 + j * 256 + tid;
      float4 v = ((const float4*)x)[i];
      bf16* po = xb + (size_t)i * 4;
      po[0] = __float2bfloat16(v.x); po[1] = __float2bfloat16(v.y);
      po[2] = __float2bfloat16(v.z); po[3] = __float2bfloat16(v.w);
    }
  } else if (bid < 876) {                // wqkv [384][1152] -> [1152][384] bf16
    int tt = bid - 768; tileT<false>(wqkv, wqkvT, 384, 1152, tt / 18, tt % 18, tid, tls);
  } else if (bid < 912) {                // wout [384][384] -> [384][384]T bf16
    int tt = bid - 876; tileT<false>(wout, woutT, 384, 384, tt / 6, tt % 6, tid, tls);
  } else {                               // mask [1024][1024] -> maskT fp16
    int tt = bid - 912; tileT<true>(mask, maskT, 1024, 1024, tt / 16, tt % 16, tid, tls);
  }
}

// ---------------- qkv GEMM: BM=128, BN=96, BK=64 -> grid 64x12 = 768 = 3 blocks/CU ----------------
__global__ __launch_bounds__(256, 3)
void k_gemm_qkv(const bf16* __restrict__ A, const bf16* __restrict__ BT,
                bf16* __restrict__ Cb, bf16* __restrict__ vT)
{
  __shared__ __align__(16) bf16 As[128 * 64];   // 16 KB
  __shared__ __align__(16) bf16 Bs[96 * 64];    // 12 KB
  const int tid = threadIdx.x;
  const int wave = tid >> 6, lane = tid & 63;
  const int lhi = lane >> 4, llo = lane & 15;
  const int wr = wave >> 1, wc = wave & 1;
  const int mBase = blockIdx.x * 128, nBase = blockIdx.y * 96;
  const int K = 384, N = 1152;

  f32x4 acc[4][3] = {};

  for (int kt = 0; kt < K; kt += 64) {
    __syncthreads();
    #pragma unroll
    for (int i = 0; i < 4; ++i) {               // A: 1024 chunks
      int c = i * 256 + tid;
      int row = c >> 3;
      int kc = (c & 7) ^ (row & 7);
      g2lds16(A + (size_t)(mBase + row) * K + kt + kc * 8, As + (c & ~63) * 8);
    }
    #pragma unroll
    for (int i = 0; i < 3; ++i) {               // B: 768 chunks
      int c = i * 256 + tid;
      int row = c >> 3;
      int kc = (c & 7) ^ (row & 7);
      g2lds16(BT + (size_t)(nBase + row) * K + kt + kc * 8, Bs + (c & ~63) * 8);
    }
    __syncthreads();
    for (int kk = 0; kk < 2; ++kk) {
      const int kc = kk * 4 + lhi;
      short8 a[4], b[3];
      #pragma unroll
      for (int mi = 0; mi < 4; ++mi)
        a[mi] = *(const short8*)(As + swz8(wr * 64 + mi * 16 + llo, kc) * 8);
      #pragma unroll
      for (int ni = 0; ni < 3; ++ni)
        b[ni] = *(const short8*)(Bs + swz8(wc * 48 + ni * 16 + llo, kc) * 8);
      #pragma unroll
      for (int mi = 0; mi < 4; ++mi)
        #pragma unroll
        for (int ni = 0; ni < 3; ++ni)
          acc[mi][ni] = MFMA16(a[mi], b[ni], acc[mi][ni]);
    }
  }

  const bool isV = (nBase >= 768);
  #pragma unroll
  for (int mi = 0; mi < 4; ++mi)
    #pragma unroll
    for (int ni = 0; ni < 3; ++ni) {
      const int colbase = nBase + wc * 48 + ni * 16;
      if (!isV) {
        #pragma unroll
        for (int j = 0; j < 4; ++j) {
          int row = mBase + wr * 64 + mi * 16 + lhi * 4 + j;
          int col = colbase + llo;
          float v = fmaxf(acc[mi][ni][j], 0.f) + 1e-6f;   // relu+eps on q,k
          Cb[(size_t)row * N + col] = __float2bfloat16(v);
        }
      } else {                                             // v-section -> vT[bh][d][n]
        int col = colbase + llo;
        int dall = col - 768, hh = dall >> 6, dd = dall & 63;
        int rowg = mBase + wr * 64 + mi * 16 + lhi * 4;
        int bb = rowg >> 10, nloc = rowg & 1023;
        ushort4v pk;
        #pragma unroll
        for (int j = 0; j < 4; ++j) pk[j] = f2bf_bits(acc[mi][ni][j]);
        *(ushort4v*)((unsigned short*)vT + (((size_t)bb * 6 + hh) * 64 + dd) * 1024 + nloc) = pk;
      }
    }
}

// ---------------- fused masked linear attention (barrier-free direct-L2 loop) ----------------
// K/V are L2-resident (256 KB per bh, XCD-aligned bid mapping) -> read MFMA
// fragments DIRECTLY from global (L2 hit), no LDS staging, no barriers in the
// loop (Common-mistake #7 / m169). LDS only for the cross-wave epilogue
// reduction. 4 waves: wq=wave&1 (q-half), wm=wave>>1 (m-half).
__global__ __launch_bounds__(256, 3)
void k_attn(const bf16* __restrict__ qkv,     // [8192][1152] (q,k sections)
            const bf16* __restrict__ vT,      // [48][64][1024]
            const __half* __restrict__ maskT, // [1024 m][1024 q] fp16
            bf16* __restrict__ out)           // [8192][384]
{
  __shared__ float OredF[2][32][65];   // 16.6 KB
  __shared__ float zredF[2][2][32];

  const int bid = blockIdx.x;
  const int bh = bid % 48, qt = bid / 48;
  const int b = bh / 6, h = bh - b * 6;
  const int tid = threadIdx.x, wave = tid >> 6, lane = tid & 63;
  const int lq = lane & 31, lh = lane >> 5;
  const int wq = wave & 1, wm = wave >> 1;
  const size_t row0 = (size_t)b * 1024;
  const int qglob = qt * 64 + wq * 32 + lq;

  // Q fragments (B-operand): lane holds Q[qglob][ks*16 + lh*8 + e]
  short8 bq[4];
  {
    const bf16* qp = qkv + (row0 + qglob) * 1152 + h * 64 + lh * 8;
    #pragma unroll
    for (int ks = 0; ks < 4; ++ks) bq[ks] = *(const short8*)(qp + ks * 16);
  }

  // per-lane base pointers for direct K/V fragment loads
  // K frag (A-op): K[row0 + mt*64 + wm*32+lq][h*64 + ks*16 + lh*8]
  const bf16* kpl = qkv + (row0 + wm * 32 + lq) * 1152 + 384 + h * 64 + lh * 8;
  // V frag (B-op): V^T[bh][db*32+lq][mt*64 + wm*32 + ks2*16 + lh*8]
  const bf16* vpl = vT + ((size_t)bh * 64 + lq) * 1024 + wm * 32 + lh * 8;
  const __half* mpl = maskT + (size_t)(wm * 32 + 4 * lh) * 1024 + qglob;

  f32x16 accO[2] = {};   // [db] : O[q 32][d 32] quadrants
  float zl = 0.f;

  #pragma unroll 2
  for (int mt = 0; mt < 16; ++mt) {
    // mask tile values
    __half mv[16];
    #pragma unroll
    for (int g = 0; g < 4; ++g)
      #pragma unroll
      for (int j = 0; j < 4; ++j)
        mv[g * 4 + j] = mpl[(size_t)(mt * 64 + 8 * g + j) * 1024];

    // S^T[32m][32q] = K . Q^T over d=64 (4 k-steps), K frags direct from L2
    f32x16 st = {};
    #pragma unroll
    for (int ks = 0; ks < 4; ++ks) {
      short8 af = *(const short8*)(kpl + (size_t)mt * 64 * 1152 + ks * 16);
      st = MFMA32(af, bq[ks], st);
    }

    // P = S*mask (f32), z partial, pack to bf16 PA-frags in registers
    float p[16];
    {
      float zp = 0.f;
      #pragma unroll
      for (int r = 0; r < 16; ++r) {
        p[r] = st[r] * __half2float(mv[r]);
        zp += p[r];
      }
      zl += zp;
    }
    int u[4][2];
    #pragma unroll
    for (int g = 0; g < 4; ++g)
      #pragma unroll
      for (int c = 0; c < 2; ++c)
        asm("v_cvt_pk_bf16_f32 %0, %1, %2"
            : "=v"(u[g][c]) : "v"(p[4 * g + 2 * c]), "v"(p[4 * g + 2 * c + 1]));

    short8 pa[2];
    #pragma unroll
    for (int ks = 0; ks < 2; ++ks) {
      int A0 = u[2 * ks][0], A0b = u[2 * ks][1];
      int A1 = u[2 * ks + 1][0], A1b = u[2 * ks + 1][1];
      int x0 = __shfl_xor(A0, 32), x1 = __shfl_xor(A0b, 32);
      int y0 = __shfl_xor(A1, 32), y1 = __shfl_xor(A1b, 32);
      int4v iv;
      iv.x = lh ? y0 : A0;    // e 0,1
      iv.y = lh ? y1 : A0b;   // e 2,3
      iv.z = lh ? A1 : x0;    // e 4,5
      iv.w = lh ? A1b : x1;   // e 6,7
      pa[ks] = *(short8*)&iv;
    }

    // O[q][d] += P . V^T  (V frags direct from L2)
    #pragma unroll
    for (int db = 0; db < 2; ++db)
      #pragma unroll
      for (int ks = 0; ks < 2; ++ks) {
        short8 vb = *(const short8*)(vpl + (size_t)db * 32 * 1024 + mt * 64 + ks * 16);
        accO[db] = MFMA32(pa[ks], vb, accO[db]);
      }
  }

  // cross-wave (wm) reduction of O and z, scale, store
  zl += __shfl_xor(zl, 32);
  zredF[wq][wm][lq] = zl;
  if (wm == 1) {
    #pragma unroll
    for (int db = 0; db < 2; ++db)
      #pragma unroll
      for (int r = 0; r < 16; ++r) {
        int q = (r & 3) + 8 * (r >> 2) + 4 * lh;
        OredF[wq][q][db * 32 + lq] = accO[db][r];
      }
  }
  __syncthreads();
  if (wm == 0) {
    #pragma unroll
    for (int r = 0; r < 16; ++r) {
      int q = (r & 3) + 8 * (r >> 2) + 4 * lh;
      float zt = zredF[wq][0][q] + zredF[wq][1][q];
      float zi = 1.f / (zt + 1e-6f);
      int n = qt * 64 + wq * 32 + q;
      size_t orow = (row0 + n) * 384 + h * 64;
      #pragma unroll
      for (int db = 0; db < 2; ++db) {
        float val = (accO[db][r] + OredF[wq][q][db * 32 + lq]) * zi;
        out[orow + db * 32 + lq] = __float2bfloat16(val);
      }
    }
  }
}

// ---------------- out-projection GEMM: 64x64 tile, 32x32 MFMA ----------------
__global__ __launch_bounds__(256, 3)
void k_gemm_out(const bf16* __restrict__ A, const bf16* __restrict__ BT,
                float* __restrict__ Cf, const float* __restrict__ bias)
{
  __shared__ __align__(16) bf16 As[64 * 64];
  __shared__ __align__(16) bf16 Bs[64 * 64];
  const int tid = threadIdx.x;
  const int wave = tid >> 6, lane = tid & 63;
  const int lq = lane & 31, lh = lane >> 5;
  const int wr = wave >> 1, wc = wave & 1;
  const int mBase = blockIdx.x * 64, nBase = blockIdx.y * 64;
  const int N = 384, K = 384;

  f32x16 acc = {};
  for (int kt = 0; kt < K; kt += 64) {
    __syncthreads();
    #pragma unroll
    for (int i = 0; i < 2; ++i) {
      int c = (wave * 2 + i) * 64 + lane;
      int row = c >> 3;
      int kc = (c & 7) ^ (row & 7);
      g2lds16(A  + (size_t)(mBase + row) * K + kt + kc * 8, As + (c & ~63) * 8);
      g2lds16(BT + (size_t)(nBase + row) * K + kt + kc * 8, Bs + (c & ~63) * 8);
    }
    __syncthreads();
    #pragma unroll
    for (int ks = 0; ks < 4; ++ks) {
      int ra = wr * 32 + lq, rb = wc * 32 + lq;
      short8 a = *(const short8*)(As + (ra * 8 + ((ks * 2 + lh) ^ (ra & 7))) * 8);
      short8 b = *(const short8*)(Bs + (rb * 8 + ((ks * 2 + lh) ^ (rb & 7))) * 8);
      acc = MFMA32(a, b, acc);
    }
  }
  #pragma unroll
  for (int r = 0; r < 16; ++r) {
    int row = mBase + wr * 32 + (r & 3) + 8 * (r >> 2) + 4 * lh;
    int col = nBase + wc * 32 + lq;
    Cf[(size_t)row * N + col] = acc[r] + bias[col];
  }
}

extern "C" void kernel_launch(void* const* d_in, const int* in_sizes, int n_in,
                              void* d_out, int out_size, void* d_ws, size_t ws_size,
                              hipStream_t stream) {
  (void)in_sizes; (void)n_in; (void)out_size; (void)ws_size;
  const float* x    = (const float*)d_in[0];   // [8,1024,384]
  const float* wqkv = (const float*)d_in[1];   // [384,1152]
  const float* wout = (const float*)d_in[2];   // [384,384]
  const float* bout = (const float*)d_in[3];   // [384]
  const float* mask = (const float*)d_in[4];   // [1024,1024]
  float* outp = (float*)d_out;

  char* ws = (char*)d_ws;
  bf16*  xb    = (bf16*)(ws);                  // 8192*384
  bf16*  wqkvT = (bf16*)(ws + 6291456);        // 1152*384
  bf16*  woutT = (bf16*)(ws + 7176192);        // 384*384
  bf16*  qkvb  = (bf16*)(ws + 7471104);        // 8192*1152 (q,k only)
  bf16*  vTb   = (bf16*)(ws + 26345472);       // 48*64*1024
  bf16*  ab    = (bf16*)(ws + 32636928);       // 8192*384
  __half* maskT = (__half*)(ws + 38928384);    // 1024*1024 fp16 (transposed)

  k_prep<<<dim3(1168), dim3(256), 0, stream>>>(
      x, xb, wqkv, (unsigned short*)wqkvT, wout, (unsigned short*)woutT,
      mask, (unsigned short*)maskT);

  k_gemm_qkv<<<dim3(64, 12), dim3(256), 0, stream>>>(xb, wqkvT, qkvb, vTb);
  k_attn<<<dim3(768), dim3(256), 0, stream>>>(qkvb, vTb, maskT, ab);
  k_gemm_out<<<dim3(128, 6), dim3(256), 0, stream>>>(ab, woutT, outp, bout);
}

// Round 19
// 60.744 us; speedup vs baseline: 1.5196x; 1.5196x over previous
//
#include <hip/hip_runtime.h>
#include <hip/hip_bf16.h>
#include <hip/hip_fp16.h>
#include <stdint.h>

typedef __hip_bfloat16 bf16;
typedef __attribute__((ext_vector_type(8))) short short8;    // 8 bf16 MFMA A/B frag
typedef __attribute__((ext_vector_type(4))) float f32x4;
typedef __attribute__((ext_vector_type(16))) float f32x16;   // 32x32 MFMA C/D
typedef __attribute__((ext_vector_type(4))) int int4v;
typedef __attribute__((ext_vector_type(4))) unsigned short ushort4v;

#define MFMA16(A,B,C) __builtin_amdgcn_mfma_f32_16x16x32_bf16(A,B,C,0,0,0)
#define MFMA32(A,B,C) __builtin_amdgcn_mfma_f32_32x32x16_bf16(A,B,C,0,0,0)

#define FENCE() asm volatile("" ::: "memory")
#define SBAR()  do { FENCE(); __builtin_amdgcn_s_barrier(); FENCE(); } while (0)
#define WAITVN(N) asm volatile("s_waitcnt vmcnt(" #N ")" ::: "memory")
#define LGKM0() asm volatile("s_waitcnt lgkmcnt(0)" ::: "memory")

// async global->LDS, 16B per lane. LDS dest = wave-uniform base + lane*16.
static __device__ __forceinline__ void g2lds16(const void* g, void* l) {
  __builtin_amdgcn_global_load_lds(
      (__attribute__((address_space(1))) void*)(g),
      (__attribute__((address_space(3))) void*)(l), 16, 0, 0);
}

// swizzled chunk index within a [rows][64 bf16] LDS tile (chunks = 8 bf16 = 16B)
static __device__ __forceinline__ int swz8(int row, int kc) {
  return row * 8 + (kc ^ (row & 7));
}

static __device__ __forceinline__ unsigned short f2bf_bits(float f) {
  bf16 t = __float2bfloat16(f); unsigned short u; __builtin_memcpy(&u, &t, 2); return u;
}
static __device__ __forceinline__ unsigned short f2h_bits(float f) {
  __half t = __float2half(f); unsigned short u; __builtin_memcpy(&u, &t, 2); return u;
}

// ---------------- merged preprocessing ----------------
template<bool HALFOUT>
static __device__ __forceinline__ void tileT(const float* __restrict__ in,
                                             unsigned short* __restrict__ out,
                                             int R, int C, int tr, int tc, int tid,
                                             float (*tls)[65]) {
  const int rr0 = tid >> 4, c4 = tid & 15;
  #pragma unroll
  for (int rr = 0; rr < 4; ++rr) {
    int r = rr0 + rr * 16;
    float4 v = *(const float4*)(in + (size_t)(tr * 64 + r) * C + tc * 64 + c4 * 4);
    tls[r][c4 * 4 + 0] = v.x; tls[r][c4 * 4 + 1] = v.y;
    tls[r][c4 * 4 + 2] = v.z; tls[r][c4 * 4 + 3] = v.w;
  }
  __syncthreads();
  #pragma unroll
  for (int rr = 0; rr < 4; ++rr) {
    int r2 = rr0 + rr * 16;
    ushort4v o;
    #pragma unroll
    for (int k = 0; k < 4; ++k) {
      float f = tls[c4 * 4 + k][r2];
      o[k] = HALFOUT ? f2h_bits(f) : f2bf_bits(f);
    }
    *(ushort4v*)(out + (size_t)(tc * 64 + r2) * R + tr * 64 + c4 * 4) = o;
  }
}

__global__ __launch_bounds__(256)
void k_prep(const float* __restrict__ x, bf16* __restrict__ xb,
            const float* __restrict__ wqkv, unsigned short* __restrict__ wqkvT,
            const float* __restrict__ wout, unsigned short* __restrict__ woutT,
            const float* __restrict__ mask, unsigned short* __restrict__ maskT) {
  __shared__ float tls[64][65];
  const int bid = blockIdx.x, tid = threadIdx.x;
  if (bid < 768) {                       // x fp32 -> bf16: 786432 float4s, 4 per thread
    #pragma unroll
    for (int j = 0; j < 4; ++j) {
      int i = bid * 1024 + j * 256 + tid;
      float4 v = ((const float4*)x)[i];
      bf16* po = xb + (size_t)i * 4;
      po[0] = __float2bfloat16(v.x); po[1] = __float2bfloat16(v.y);
      po[2] = __float2bfloat16(v.z); po[3] = __float2bfloat16(v.w);
    }
  } else if (bid < 876) {                // wqkv [384][1152] -> [1152][384] bf16
    int tt = bid - 768; tileT<false>(wqkv, wqkvT, 384, 1152, tt / 18, tt % 18, tid, tls);
  } else if (bid < 912) {                // wout [384][384] -> [384][384]T bf16
    int tt = bid - 876; tileT<false>(wout, woutT, 384, 384, tt / 6, tt % 6, tid, tls);
  } else {                               // mask [1024][1024] -> maskT fp16
    int tt = bid - 912; tileT<true>(mask, maskT, 1024, 1024, tt / 16, tt % 16, tid, tls);
  }
}

// ---------------- qkv GEMM: BM=128, BN=96, BK=64 -> grid 64x12 = 768 = 3 blocks/CU ----------------
__global__ __launch_bounds__(256, 3)
void k_gemm_qkv(const bf16* __restrict__ A, const bf16* __restrict__ BT,
                bf16* __restrict__ Cb, bf16* __restrict__ vT)
{
  __shared__ __align__(16) bf16 As[128 * 64];   // 16 KB
  __shared__ __align__(16) bf16 Bs[96 * 64];    // 12 KB
  const int tid = threadIdx.x;
  const int wave = tid >> 6, lane = tid & 63;
  const int lhi = lane >> 4, llo = lane & 15;
  const int wr = wave >> 1, wc = wave & 1;
  const int mBase = blockIdx.x * 128, nBase = blockIdx.y * 96;
  const int K = 384, N = 1152;

  f32x4 acc[4][3] = {};

  for (int kt = 0; kt < K; kt += 64) {
    __syncthreads();
    #pragma unroll
    for (int i = 0; i < 4; ++i) {               // A: 1024 chunks
      int c = i * 256 + tid;
      int row = c >> 3;
      int kc = (c & 7) ^ (row & 7);
      g2lds16(A + (size_t)(mBase + row) * K + kt + kc * 8, As + (c & ~63) * 8);
    }
    #pragma unroll
    for (int i = 0; i < 3; ++i) {               // B: 768 chunks
      int c = i * 256 + tid;
      int row = c >> 3;
      int kc = (c & 7) ^ (row & 7);
      g2lds16(BT + (size_t)(nBase + row) * K + kt + kc * 8, Bs + (c & ~63) * 8);
    }
    __syncthreads();
    for (int kk = 0; kk < 2; ++kk) {
      const int kc = kk * 4 + lhi;
      short8 a[4], b[3];
      #pragma unroll
      for (int mi = 0; mi < 4; ++mi)
        a[mi] = *(const short8*)(As + swz8(wr * 64 + mi * 16 + llo, kc) * 8);
      #pragma unroll
      for (int ni = 0; ni < 3; ++ni)
        b[ni] = *(const short8*)(Bs + swz8(wc * 48 + ni * 16 + llo, kc) * 8);
      #pragma unroll
      for (int mi = 0; mi < 4; ++mi)
        #pragma unroll
        for (int ni = 0; ni < 3; ++ni)
          acc[mi][ni] = MFMA16(a[mi], b[ni], acc[mi][ni]);
    }
  }

  const bool isV = (nBase >= 768);
  #pragma unroll
  for (int mi = 0; mi < 4; ++mi)
    #pragma unroll
    for (int ni = 0; ni < 3; ++ni) {
      const int colbase = nBase + wc * 48 + ni * 16;
      if (!isV) {
        #pragma unroll
        for (int j = 0; j < 4; ++j) {
          int row = mBase + wr * 64 + mi * 16 + lhi * 4 + j;
          int col = colbase + llo;
          float v = fmaxf(acc[mi][ni][j], 0.f) + 1e-6f;   // relu+eps on q,k
          Cb[(size_t)row * N + col] = __float2bfloat16(v);
        }
      } else {                                             // v-section -> vT[bh][d][n]
        int col = colbase + llo;
        int dall = col - 768, hh = dall >> 6, dd = dall & 63;
        int rowg = mBase + wr * 64 + mi * 16 + lhi * 4;
        int bb = rowg >> 10, nloc = rowg & 1023;
        ushort4v pk;
        #pragma unroll
        for (int j = 0; j < 4; ++j) pk[j] = f2bf_bits(acc[mi][ni][j]);
        *(ushort4v*)((unsigned short*)vT + (((size_t)bb * 6 + hh) * 64 + dd) * 1024 + nloc) = pk;
      }
    }
}

// ---------------- fused masked linear attention (2-buffer, 4 blocks/CU) ----------------
// R11-proven robust counted-vmcnt scheme (passed pre+post): only stage DMAs in
// the vmcnt window at WAITVN(4); mask loads issued AFTER the start barrier;
// end barrier preceded by lgkmcnt(0)+sched_barrier(0) (rule #18).
// LDS shrunk to 33 KB (2 K/V buffers; epilogue reduction aliases them) ->
// 4 blocks/CU = 16 waves (+33% TLP on this latency-bound kernel).
__global__ __launch_bounds__(256, 4)
void k_attn(const bf16* __restrict__ qkv,     // [8192][1152] (q,k sections)
            const bf16* __restrict__ vT,      // [48][64][1024]
            const __half* __restrict__ maskT, // [1024 m][1024 q] fp16
            bf16* __restrict__ out)           // [8192][384]
{
  __shared__ __align__(16) char smem[33280];
  bf16* KsB = (bf16*)smem;                    // 2 x [64*64] (16 KB)
  bf16* VsB = KsB + 2 * 4096;                 // 2 x [64*64] (16 KB)
  float* OredF = (float*)smem;                // [2][32][65] = 16640 B (alias, post-loop)
  float* zredF = (float*)(smem + 32768);      // [2][2][32]  = 512 B

  const int bid = blockIdx.x;
  const int bh = bid % 48, qt = bid / 48;
  const int b = bh / 6, h = bh - b * 6;
  const int tid = threadIdx.x, wave = tid >> 6, lane = tid & 63;
  const int lq = lane & 31, lh = lane >> 5;
  const int wq = wave & 1, wm = wave >> 1;
  const size_t row0 = (size_t)b * 1024;
  const int qglob = qt * 64 + wq * 32 + lq;

  auto stageKV = [&](int mt, int buf) {
    #pragma unroll
    for (int i = 0; i < 2; ++i) {
      int c = (wave * 2 + i) * 64 + lane;
      int row = c >> 3;
      int kc = (c & 7) ^ (row & 7);
      g2lds16(qkv + (row0 + mt * 64 + row) * 1152 + 384 + h * 64 + kc * 8,
              KsB + buf * 4096 + (c & ~63) * 8);
      g2lds16(vT + ((size_t)bh * 64 + row) * 1024 + mt * 64 + kc * 8,
              VsB + buf * 4096 + (c & ~63) * 8);
    }
  };

  // Q fragments (B-operand): lane holds Q[qglob][ks*16 + lh*8 + e]
  short8 bq[4];
  {
    const bf16* qp = qkv + (row0 + qglob) * 1152 + h * 64 + lh * 8;
    #pragma unroll
    for (int ks = 0; ks < 4; ++ks) bq[ks] = *(const short8*)(qp + ks * 16);
  }
  stageKV(0, 0);

  f32x16 accO[2] = {};   // [db] : O[q 32][d 32] quadrants
  float zl = 0.f;

  #pragma unroll 1
  for (int mt = 0; mt < 16; ++mt) {
    const int cur = mt & 1;
    const bf16* Kc = KsB + cur * 4096;
    const bf16* Vc = VsB + cur * 4096;

    if (mt < 15) {
      stageKV(mt + 1, cur ^ 1);
      WAITVN(4);             // window holds only stage DMAs: retire stage(mt),
    } else {                 // keep stage(mt+1)'s 4 in flight
      WAITVN(0);
    }
    SBAR();                  // buf[cur] fully populated across waves

    // mask tile values (issued after the barrier; latency hides under QK^T)
    __half mv[16];
    {
      const int mrow0 = mt * 64 + wm * 32 + 4 * lh;
      #pragma unroll
      for (int g = 0; g < 4; ++g)
        #pragma unroll
        for (int j = 0; j < 4; ++j)
          mv[g * 4 + j] = maskT[(size_t)(mrow0 + 8 * g + j) * 1024 + qglob];
    }

    // S^T[32m][32q] = K . Q^T over d=64 (4 k-steps)
    f32x16 st = {};
    #pragma unroll
    for (int ks = 0; ks < 4; ++ks) {
      int row = wm * 32 + lq;
      int cc = (ks * 2 + lh) ^ (row & 7);
      short8 af = *(const short8*)(Kc + (row * 8 + cc) * 8);
      st = MFMA32(af, bq[ks], st);
    }

    // P = S*mask (f32), z partial, pack to bf16 PA-frags in registers
    float p[16];
    {
      float zp = 0.f;
      #pragma unroll
      for (int r = 0; r < 16; ++r) {
        p[r] = st[r] * __half2float(mv[r]);
        zp += p[r];
      }
      zl += zp;
    }
    int u[4][2];
    #pragma unroll
    for (int g = 0; g < 4; ++g)
      #pragma unroll
      for (int c = 0; c < 2; ++c)
        asm("v_cvt_pk_bf16_f32 %0, %1, %2"
            : "=v"(u[g][c]) : "v"(p[4 * g + 2 * c]), "v"(p[4 * g + 2 * c + 1]));

    short8 pa[2];
    #pragma unroll
    for (int ks = 0; ks < 2; ++ks) {
      int A0 = u[2 * ks][0], A0b = u[2 * ks][1];
      int A1 = u[2 * ks + 1][0], A1b = u[2 * ks + 1][1];
      int x0 = __shfl_xor(A0, 32), x1 = __shfl_xor(A0b, 32);
      int y0 = __shfl_xor(A1, 32), y1 = __shfl_xor(A1b, 32);
      int4v iv;
      iv.x = lh ? y0 : A0;    // e 0,1
      iv.y = lh ? y1 : A0b;   // e 2,3
      iv.z = lh ? A1 : x0;    // e 4,5
      iv.w = lh ? A1b : x1;   // e 6,7
      pa[ks] = *(short8*)&iv;
    }

    // O[q][d] += P . V^T  (b-frag rows = V^T[d][m])
    #pragma unroll
    for (int db = 0; db < 2; ++db)
      #pragma unroll
      for (int ks = 0; ks < 2; ++ks) {
        int row = db * 32 + lq;
        int cc = (wm * 4 + ks * 2 + lh) ^ (row & 7);
        short8 vb = *(const short8*)(Vc + (row * 8 + cc) * 8);
        accO[db] = MFMA32(pa[ks], vb, accO[db]);
      }

    // own ds_reads complete and pinned above the barrier (rule #18)
    LGKM0();
    __builtin_amdgcn_sched_barrier(0);
    SBAR();                  // all waves done reading buf[cur]
  }

  // cross-wave (wm) reduction of O and z, scale, store (OredF aliases K/V bufs;
  // safe: final SBAR above guarantees all waves' LDS reads are retired)
  zl += __shfl_xor(zl, 32);
  zredF[(wq * 2 + wm) * 32 + lq] = zl;
  if (wm == 1) {
    #pragma unroll
    for (int db = 0; db < 2; ++db)
      #pragma unroll
      for (int r = 0; r < 16; ++r) {
        int q = (r & 3) + 8 * (r >> 2) + 4 * lh;
        OredF[(wq * 32 + q) * 65 + db * 32 + lq] = accO[db][r];
      }
  }
  __syncthreads();
  if (wm == 0) {
    #pragma unroll
    for (int r = 0; r < 16; ++r) {
      int q = (r & 3) + 8 * (r >> 2) + 4 * lh;
      float zt = zredF[wq * 2 * 32 + q] + zredF[(wq * 2 + 1) * 32 + q];
      float zi = 1.f / (zt + 1e-6f);
      int n = qt * 64 + wq * 32 + q;
      size_t orow = (row0 + n) * 384 + h * 64;
      #pragma unroll
      for (int db = 0; db < 2; ++db) {
        float val = (accO[db][r] + OredF[(wq * 32 + q) * 65 + db * 32 + lq]) * zi;
        out[orow + db * 32 + lq] = __float2bfloat16(val);
      }
    }
  }
}

// ---------------- out-projection GEMM: 64x64 tile, 32x32 MFMA ----------------
__global__ __launch_bounds__(256, 3)
void k_gemm_out(const bf16* __restrict__ A, const bf16* __restrict__ BT,
                float* __restrict__ Cf, const float* __restrict__ bias)
{
  __shared__ __align__(16) bf16 As[64 * 64];
  __shared__ __align__(16) bf16 Bs[64 * 64];
  const int tid = threadIdx.x;
  const int wave = tid >> 6, lane = tid & 63;
  const int lq = lane & 31, lh = lane >> 5;
  const int wr = wave >> 1, wc = wave & 1;
  const int mBase = blockIdx.x * 64, nBase = blockIdx.y * 64;
  const int N = 384, K = 384;

  f32x16 acc = {};
  for (int kt = 0; kt < K; kt += 64) {
    __syncthreads();
    #pragma unroll
    for (int i = 0; i < 2; ++i) {
      int c = (wave * 2 + i) * 64 + lane;
      int row = c >> 3;
      int kc = (c & 7) ^ (row & 7);
      g2lds16(A  + (size_t)(mBase + row) * K + kt + kc * 8, As + (c & ~63) * 8);
      g2lds16(BT + (size_t)(nBase + row) * K + kt + kc * 8, Bs + (c & ~63) * 8);
    }
    __syncthreads();
    #pragma unroll
    for (int ks = 0; ks < 4; ++ks) {
      int ra = wr * 32 + lq, rb = wc * 32 + lq;
      short8 a = *(const short8*)(As + (ra * 8 + ((ks * 2 + lh) ^ (ra & 7))) * 8);
      short8 b = *(const short8*)(Bs + (rb * 8 + ((ks * 2 + lh) ^ (rb & 7))) * 8);
      acc = MFMA32(a, b, acc);
    }
  }
  #pragma unroll
  for (int r = 0; r < 16; ++r) {
    int row = mBase + wr * 32 + (r & 3) + 8 * (r >> 2) + 4 * lh;
    int col = nBase + wc * 32 + lq;
    Cf[(size_t)row * N + col] = acc[r] + bias[col];
  }
}

extern "C" void kernel_launch(void* const* d_in, const int* in_sizes, int n_in,
                              void* d_out, int out_size, void* d_ws, size_t ws_size,
                              hipStream_t stream) {
  (void)in_sizes; (void)n_in; (void)out_size; (void)ws_size;
  const float* x    = (const float*)d_in[0];   // [8,1024,384]
  const float* wqkv = (const float*)d_in[1];   // [384,1152]
  const float* wout = (const float*)d_in[2];   // [384,384]
  const float* bout = (const float*)d_in[3];   // [384]
  const float* mask = (const float*)d_in[4];   // [1024,1024]
  float* outp = (float*)d_out;

  char* ws = (char*)d_ws;
  bf16*  xb    = (bf16*)(ws);                  // 8192*384
  bf16*  wqkvT = (bf16*)(ws + 6291456);        // 1152*384
  bf16*  woutT = (bf16*)(ws + 7176192);        // 384*384
  bf16*  qkvb  = (bf16*)(ws + 7471104);        // 8192*1152 (q,k only)
  bf16*  vTb   = (bf16*)(ws + 26345472);       // 48*64*1024
  bf16*  ab    = (bf16*)(ws + 32636928);       // 8192*384
  __half* maskT = (__half*)(ws + 38928384);    // 1024*1024 fp16 (transposed)

  k_prep<<<dim3(1168), dim3(256), 0, stream>>>(
      x, xb, wqkv, (unsigned short*)wqkvT, wout, (unsigned short*)woutT,
      mask, (unsigned short*)maskT);

  k_gemm_qkv<<<dim3(64, 12), dim3(256), 0, stream>>>(xb, wqkvT, qkvb, vTb);
  k_attn<<<dim3(768), dim3(256), 0, stream>>>(qkvb, vTb, maskT, ab);
  k_gemm_out<<<dim3(128, 6), dim3(256), 0, stream>>>(ab, woutT, outp, bout);
}

// Round 20
// 57.368 us; speedup vs baseline: 1.6090x; 1.0588x over previous
//
#include <hip/hip_runtime.h>
#include <hip/hip_bf16.h>
#include <hip/hip_fp16.h>
#include <stdint.h>

typedef __hip_bfloat16 bf16;
typedef __attribute__((ext_vector_type(8))) short short8;    // 8 bf16 MFMA A/B frag
typedef __attribute__((ext_vector_type(4))) float f32x4;
typedef __attribute__((ext_vector_type(16))) float f32x16;   // 32x32 MFMA C/D
typedef __attribute__((ext_vector_type(4))) int int4v;
typedef __attribute__((ext_vector_type(4))) unsigned short ushort4v;

#define MFMA16(A,B,C) __builtin_amdgcn_mfma_f32_16x16x32_bf16(A,B,C,0,0,0)
#define MFMA32(A,B,C) __builtin_amdgcn_mfma_f32_32x32x16_bf16(A,B,C,0,0,0)

#define FENCE() asm volatile("" ::: "memory")
#define SBAR()  do { FENCE(); __builtin_amdgcn_s_barrier(); FENCE(); } while (0)
#define WAITVN(N) asm volatile("s_waitcnt vmcnt(" #N ")" ::: "memory")
#define LGKM0() asm volatile("s_waitcnt lgkmcnt(0)" ::: "memory")

// async global->LDS, 16B per lane. LDS dest = wave-uniform base + lane*16.
static __device__ __forceinline__ void g2lds16(const void* g, void* l) {
  __builtin_amdgcn_global_load_lds(
      (__attribute__((address_space(1))) void*)(g),
      (__attribute__((address_space(3))) void*)(l), 16, 0, 0);
}

// swizzled chunk index within a [rows][64 bf16] LDS tile (chunks = 8 bf16 = 16B)
static __device__ __forceinline__ int swz8(int row, int kc) {
  return row * 8 + (kc ^ (row & 7));
}

static __device__ __forceinline__ unsigned short f2bf_bits(float f) {
  bf16 t = __float2bfloat16(f); unsigned short u; __builtin_memcpy(&u, &t, 2); return u;
}
static __device__ __forceinline__ unsigned short f2h_bits(float f) {
  __half t = __float2half(f); unsigned short u; __builtin_memcpy(&u, &t, 2); return u;
}

// ---------------- merged preprocessing ----------------
template<bool HALFOUT>
static __device__ __forceinline__ void tileT(const float* __restrict__ in,
                                             unsigned short* __restrict__ out,
                                             int R, int C, int tr, int tc, int tid,
                                             float (*tls)[65]) {
  const int rr0 = tid >> 4, c4 = tid & 15;
  #pragma unroll
  for (int rr = 0; rr < 4; ++rr) {
    int r = rr0 + rr * 16;
    float4 v = *(const float4*)(in + (size_t)(tr * 64 + r) * C + tc * 64 + c4 * 4);
    tls[r][c4 * 4 + 0] = v.x; tls[r][c4 * 4 + 1] = v.y;
    tls[r][c4 * 4 + 2] = v.z; tls[r][c4 * 4 + 3] = v.w;
  }
  __syncthreads();
  #pragma unroll
  for (int rr = 0; rr < 4; ++rr) {
    int r2 = rr0 + rr * 16;
    ushort4v o;
    #pragma unroll
    for (int k = 0; k < 4; ++k) {
      float f = tls[c4 * 4 + k][r2];
      o[k] = HALFOUT ? f2h_bits(f) : f2bf_bits(f);
    }
    *(ushort4v*)(out + (size_t)(tc * 64 + r2) * R + tr * 64 + c4 * 4) = o;
  }
}

__global__ __launch_bounds__(256)
void k_prep(const float* __restrict__ x, bf16* __restrict__ xb,
            const float* __restrict__ wqkv, unsigned short* __restrict__ wqkvT,
            const float* __restrict__ wout, unsigned short* __restrict__ woutT,
            const float* __restrict__ mask, unsigned short* __restrict__ maskT) {
  __shared__ float tls[64][65];
  const int bid = blockIdx.x, tid = threadIdx.x;
  if (bid < 768) {                       // x fp32 -> bf16: 786432 float4s, 4 per thread
    #pragma unroll
    for (int j = 0; j < 4; ++j) {
      int i = bid * 1024 + j * 256 + tid;
      float4 v = ((const float4*)x)[i];
      bf16* po = xb + (size_t)i * 4;
      po[0] = __float2bfloat16(v.x); po[1] = __float2bfloat16(v.y);
      po[2] = __float2bfloat16(v.z); po[3] = __float2bfloat16(v.w);
    }
  } else if (bid < 876) {                // wqkv [384][1152] -> [1152][384] bf16
    int tt = bid - 768; tileT<false>(wqkv, wqkvT, 384, 1152, tt / 18, tt % 18, tid, tls);
  } else if (bid < 912) {                // wout [384][384] -> [384][384]T bf16
    int tt = bid - 876; tileT<false>(wout, woutT, 384, 384, tt / 6, tt % 6, tid, tls);
  } else {                               // mask [1024][1024] -> maskT fp16
    int tt = bid - 912; tileT<true>(mask, maskT, 1024, 1024, tt / 16, tt % 16, tid, tls);
  }
}

// ---------------- qkv GEMM: BM=128, BN=96, BK=64 -> grid 64x12 = 768 = 3 blocks/CU ----------------
__global__ __launch_bounds__(256, 3)
void k_gemm_qkv(const bf16* __restrict__ A, const bf16* __restrict__ BT,
                bf16* __restrict__ Cb, bf16* __restrict__ vT)
{
  __shared__ __align__(16) bf16 As[128 * 64];   // 16 KB
  __shared__ __align__(16) bf16 Bs[96 * 64];    // 12 KB
  const int tid = threadIdx.x;
  const int wave = tid >> 6, lane = tid & 63;
  const int lhi = lane >> 4, llo = lane & 15;
  const int wr = wave >> 1, wc = wave & 1;
  const int mBase = blockIdx.x * 128, nBase = blockIdx.y * 96;
  const int K = 384, N = 1152;

  f32x4 acc[4][3] = {};

  for (int kt = 0; kt < K; kt += 64) {
    __syncthreads();
    #pragma unroll
    for (int i = 0; i < 4; ++i) {               // A: 1024 chunks
      int c = i * 256 + tid;
      int row = c >> 3;
      int kc = (c & 7) ^ (row & 7);
      g2lds16(A + (size_t)(mBase + row) * K + kt + kc * 8, As + (c & ~63) * 8);
    }
    #pragma unroll
    for (int i = 0; i < 3; ++i) {               // B: 768 chunks
      int c = i * 256 + tid;
      int row = c >> 3;
      int kc = (c & 7) ^ (row & 7);
      g2lds16(BT + (size_t)(nBase + row) * K + kt + kc * 8, Bs + (c & ~63) * 8);
    }
    __syncthreads();
    for (int kk = 0; kk < 2; ++kk) {
      const int kc = kk * 4 + lhi;
      short8 a[4], b[3];
      #pragma unroll
      for (int mi = 0; mi < 4; ++mi)
        a[mi] = *(const short8*)(As + swz8(wr * 64 + mi * 16 + llo, kc) * 8);
      #pragma unroll
      for (int ni = 0; ni < 3; ++ni)
        b[ni] = *(const short8*)(Bs + swz8(wc * 48 + ni * 16 + llo, kc) * 8);
      #pragma unroll
      for (int mi = 0; mi < 4; ++mi)
        #pragma unroll
        for (int ni = 0; ni < 3; ++ni)
          acc[mi][ni] = MFMA16(a[mi], b[ni], acc[mi][ni]);
    }
  }

  const bool isV = (nBase >= 768);
  #pragma unroll
  for (int mi = 0; mi < 4; ++mi)
    #pragma unroll
    for (int ni = 0; ni < 3; ++ni) {
      const int colbase = nBase + wc * 48 + ni * 16;
      if (!isV) {
        #pragma unroll
        for (int j = 0; j < 4; ++j) {
          int row = mBase + wr * 64 + mi * 16 + lhi * 4 + j;
          int col = colbase + llo;
          float v = fmaxf(acc[mi][ni][j], 0.f) + 1e-6f;   // relu+eps on q,k
          Cb[(size_t)row * N + col] = __float2bfloat16(v);
        }
      } else {                                             // v-section -> vT[bh][d][n]
        int col = colbase + llo;
        int dall = col - 768, hh = dall >> 6, dd = dall & 63;
        int rowg = mBase + wr * 64 + mi * 16 + lhi * 4;
        int bb = rowg >> 10, nloc = rowg & 1023;
        ushort4v pk;
        #pragma unroll
        for (int j = 0; j < 4; ++j) pk[j] = f2bf_bits(acc[mi][ni][j]);
        *(ushort4v*)((unsigned short*)vT + (((size_t)bb * 6 + hh) * 64 + dd) * 1024 + nloc) = pk;
      }
    }
}

// ---------------- fused masked linear attention (3-buffer, 2-iter-deep staging) ----------------
// Deepened R13/R17 pipeline: stage(t+2) issued at iter t -> DMA flight = 2
// iterations. Per-wave vmem queue at iter-t wait: [stage(t)4, mask(t)16,
// stage(t+1)4] -> WAITVN(4) retires stage(t)+mask(t), keeps exactly stage(t+1)
// (window exact under any schedule). LGKM0 before the single SBAR retires all
// reads of the buffer stage(t+2) will overwrite (issued after the SBAR).
__global__ __launch_bounds__(256, 3)
void k_attn(const bf16* __restrict__ qkv,     // [8192][1152] (q,k sections)
            const bf16* __restrict__ vT,      // [48][64][1024]
            const __half* __restrict__ maskT, // [1024 m][1024 q] fp16
            bf16* __restrict__ out)           // [8192][384]
{
  __shared__ __align__(16) char smem[49664];
  bf16* KsB = (bf16*)smem;                    // 3 x [64*64] (24 KB)
  bf16* VsB = KsB + 3 * 4096;                 // 3 x [64*64] (24 KB)
  float* OredF = (float*)smem;                // [2][32][65] = 16640 B (alias, post-loop)
  float* zredF = (float*)(smem + 49152);      // [2][2][32]  = 512 B

  const int bid = blockIdx.x;
  const int bh = bid % 48, qt = bid / 48;
  const int b = bh / 6, h = bh - b * 6;
  const int tid = threadIdx.x, wave = tid >> 6, lane = tid & 63;
  const int lq = lane & 31, lh = lane >> 5;
  const int wq = wave & 1, wm = wave >> 1;
  const size_t row0 = (size_t)b * 1024;
  const int qglob = qt * 64 + wq * 32 + lq;

  auto stageKV = [&](int mt, int buf) {
    #pragma unroll
    for (int i = 0; i < 2; ++i) {
      int c = (wave * 2 + i) * 64 + lane;
      int row = c >> 3;
      int kc = (c & 7) ^ (row & 7);
      g2lds16(qkv + (row0 + mt * 64 + row) * 1152 + 384 + h * 64 + kc * 8,
              KsB + buf * 4096 + (c & ~63) * 8);
      g2lds16(vT + ((size_t)bh * 64 + row) * 1024 + mt * 64 + kc * 8,
              VsB + buf * 4096 + (c & ~63) * 8);
    }
  };
  auto loadMask = [&](int mt, __half (&mv)[16]) {
    const int mrow0 = mt * 64 + wm * 32 + 4 * lh;
    #pragma unroll
    for (int g = 0; g < 4; ++g)
      #pragma unroll
      for (int j = 0; j < 4; ++j)
        mv[g * 4 + j] = maskT[(size_t)(mrow0 + 8 * g + j) * 1024 + qglob];
  };

  // Q fragments (B-operand): lane holds Q[qglob][ks*16 + lh*8 + e]
  short8 bq[4];
  {
    const bf16* qp = qkv + (row0 + qglob) * 1152 + h * 64 + lh * 8;
    #pragma unroll
    for (int ks = 0; ks < 4; ++ks) bq[ks] = *(const short8*)(qp + ks * 16);
  }

  f32x16 accO[2] = {};   // [db] : O[q 32][d 32] quadrants
  float zl = 0.f;

  __half mvA[16], mvB[16];
  // prologue: queue = [stage(0)4, mask(0)16, stage(1)4]
  stageKV(0, 0);
  loadMask(0, mvA);
  stageKV(1, 1);

  auto iter = [&](int t, __half (&mvUse)[16], __half (&mvPre)[16]) {
    const int bc = t % 3;
    const bf16* Kc = KsB + bc * 4096;
    const bf16* Vc = VsB + bc * 4096;

    if (t < 15) {
      WAITVN(4);           // retires stage(t)+mask(t); keeps stage(t+1) in flight
    } else {
      WAITVN(0);
    }
    LGKM0();               // all reads of buf[(t+2)%3] (== buf[(t-1)%3]) retired
    SBAR();                // buf[bc] fully populated across waves

    if (t < 15) loadMask(t + 1, mvPre);       // mask flight = 1 iter
    if (t < 14) stageKV(t + 2, (t + 2) % 3);  // stage flight = 2 iters

    // S^T[32m][32q] = K . Q^T over d=64 (4 k-steps)
    f32x16 st = {};
    #pragma unroll
    for (int ks = 0; ks < 4; ++ks) {
      int row = wm * 32 + lq;
      int cc = (ks * 2 + lh) ^ (row & 7);
      short8 af = *(const short8*)(Kc + (row * 8 + cc) * 8);
      st = MFMA32(af, bq[ks], st);
    }

    // P = S*mask (f32), z partial, pack to bf16 PA-frags in registers
    float p[16];
    {
      float zp = 0.f;
      #pragma unroll
      for (int r = 0; r < 16; ++r) {
        p[r] = st[r] * __half2float(mvUse[r]);
        zp += p[r];
      }
      zl += zp;
    }
    int u[4][2];
    #pragma unroll
    for (int g = 0; g < 4; ++g)
      #pragma unroll
      for (int c = 0; c < 2; ++c)
        asm("v_cvt_pk_bf16_f32 %0, %1, %2"
            : "=v"(u[g][c]) : "v"(p[4 * g + 2 * c]), "v"(p[4 * g + 2 * c + 1]));

    short8 pa[2];
    #pragma unroll
    for (int ks = 0; ks < 2; ++ks) {
      int A0 = u[2 * ks][0], A0b = u[2 * ks][1];
      int A1 = u[2 * ks + 1][0], A1b = u[2 * ks + 1][1];
      int x0 = __shfl_xor(A0, 32), x1 = __shfl_xor(A0b, 32);
      int y0 = __shfl_xor(A1, 32), y1 = __shfl_xor(A1b, 32);
      int4v iv;
      iv.x = lh ? y0 : A0;    // e 0,1
      iv.y = lh ? y1 : A0b;   // e 2,3
      iv.z = lh ? A1 : x0;    // e 4,5
      iv.w = lh ? A1b : x1;   // e 6,7
      pa[ks] = *(short8*)&iv;
    }

    // O[q][d] += P . V^T  (b-frag rows = V^T[d][m])
    #pragma unroll
    for (int db = 0; db < 2; ++db)
      #pragma unroll
      for (int ks = 0; ks < 2; ++ks) {
        int row = db * 32 + lq;
        int cc = (wm * 4 + ks * 2 + lh) ^ (row & 7);
        short8 vb = *(const short8*)(Vc + (row * 8 + cc) * 8);
        accO[db] = MFMA32(pa[ks], vb, accO[db]);
      }
  };

  #pragma unroll 1
  for (int mt2 = 0; mt2 < 8; ++mt2) {
    iter(2 * mt2,     mvA, mvB);
    iter(2 * mt2 + 1, mvB, mvA);
  }
  __syncthreads();   // all waves done with K/V buffers before Ored alias writes

  // cross-wave (wm) reduction of O and z, scale, store
  zl += __shfl_xor(zl, 32);
  zredF[(wq * 2 + wm) * 32 + lq] = zl;
  if (wm == 1) {
    #pragma unroll
    for (int db = 0; db < 2; ++db)
      #pragma unroll
      for (int r = 0; r < 16; ++r) {
        int q = (r & 3) + 8 * (r >> 2) + 4 * lh;
        OredF[(wq * 32 + q) * 65 + db * 32 + lq] = accO[db][r];
      }
  }
  __syncthreads();
  if (wm == 0) {
    #pragma unroll
    for (int r = 0; r < 16; ++r) {
      int q = (r & 3) + 8 * (r >> 2) + 4 * lh;
      float zt = zredF[wq * 2 * 32 + q] + zredF[(wq * 2 + 1) * 32 + q];
      float zi = 1.f / (zt + 1e-6f);
      int n = qt * 64 + wq * 32 + q;
      size_t orow = (row0 + n) * 384 + h * 64;
      #pragma unroll
      for (int db = 0; db < 2; ++db) {
        float val = (accO[db][r] + OredF[(wq * 32 + q) * 65 + db * 32 + lq]) * zi;
        out[orow + db * 32 + lq] = __float2bfloat16(val);
      }
    }
  }
}

// ---------------- out-projection GEMM: 64x64 tile, 32x32 MFMA ----------------
__global__ __launch_bounds__(256, 3)
void k_gemm_out(const bf16* __restrict__ A, const bf16* __restrict__ BT,
                float* __restrict__ Cf, const float* __restrict__ bias)
{
  __shared__ __align__(16) bf16 As[64 * 64];
  __shared__ __align__(16) bf16 Bs[64 * 64];
  const int tid = threadIdx.x;
  const int wave = tid >> 6, lane = tid & 63;
  const int lq = lane & 31, lh = lane >> 5;
  const int wr = wave >> 1, wc = wave & 1;
  const int mBase = blockIdx.x * 64, nBase = blockIdx.y * 64;
  const int N = 384, K = 384;

  f32x16 acc = {};
  for (int kt = 0; kt < K; kt += 64) {
    __syncthreads();
    #pragma unroll
    for (int i = 0; i < 2; ++i) {
      int c = (wave * 2 + i) * 64 + lane;
      int row = c >> 3;
      int kc = (c & 7) ^ (row & 7);
      g2lds16(A  + (size_t)(mBase + row) * K + kt + kc * 8, As + (c & ~63) * 8);
      g2lds16(BT + (size_t)(nBase + row) * K + kt + kc * 8, Bs + (c & ~63) * 8);
    }
    __syncthreads();
    #pragma unroll
    for (int ks = 0; ks < 4; ++ks) {
      int ra = wr * 32 + lq, rb = wc * 32 + lq;
      short8 a = *(const short8*)(As + (ra * 8 + ((ks * 2 + lh) ^ (ra & 7))) * 8);
      short8 b = *(const short8*)(Bs + (rb * 8 + ((ks * 2 + lh) ^ (rb & 7))) * 8);
      acc = MFMA32(a, b, acc);
    }
  }
  #pragma unroll
  for (int r = 0; r < 16; ++r) {
    int row = mBase + wr * 32 + (r & 3) + 8 * (r >> 2) + 4 * lh;
    int col = nBase + wc * 32 + lq;
    Cf[(size_t)row * N + col] = acc[r] + bias[col];
  }
}

extern "C" void kernel_launch(void* const* d_in, const int* in_sizes, int n_in,
                              void* d_out, int out_size, void* d_ws, size_t ws_size,
                              hipStream_t stream) {
  (void)in_sizes; (void)n_in; (void)out_size; (void)ws_size;
  const float* x    = (const float*)d_in[0];   // [8,1024,384]
  const float* wqkv = (const float*)d_in[1];   // [384,1152]
  const float* wout = (const float*)d_in[2];   // [384,384]
  const float* bout = (const float*)d_in[3];   // [384]
  const float* mask = (const float*)d_in[4];   // [1024,1024]
  float* outp = (float*)d_out;

  char* ws = (char*)d_ws;
  bf16*  xb    = (bf16*)(ws);                  // 8192*384
  bf16*  wqkvT = (bf16*)(ws + 6291456);        // 1152*384
  bf16*  woutT = (bf16*)(ws + 7176192);        // 384*384
  bf16*  qkvb  = (bf16*)(ws + 7471104);        // 8192*1152 (q,k only)
  bf16*  vTb   = (bf16*)(ws + 26345472);       // 48*64*1024
  bf16*  ab    = (bf16*)(ws + 32636928);       // 8192*384
  __half* maskT = (__half*)(ws + 38928384);    // 1024*1024 fp16 (transposed)

  k_prep<<<dim3(1168), dim3(256), 0, stream>>>(
      x, xb, wqkv, (unsigned short*)wqkvT, wout, (unsigned short*)woutT,
      mask, (unsigned short*)maskT);

  k_gemm_qkv<<<dim3(64, 12), dim3(256), 0, stream>>>(xb, wqkvT, qkvb, vTb);
  k_attn<<<dim3(768), dim3(256), 0, stream>>>(qkvb, vTb, maskT, ab);
  k_gemm_out<<<dim3(128, 6), dim3(256), 0, stream>>>(ab, woutT, outp, bout);
}

// Round 21
// 56.724 us; speedup vs baseline: 1.6273x; 1.0114x over previous
//
#include <hip/hip_runtime.h>
#include <hip/hip_bf16.h>
#include <hip/hip_fp16.h>
#include <stdint.h>

typedef __hip_bfloat16 bf16;
typedef __attribute__((ext_vector_type(8))) short short8;    // 8 bf16 MFMA A/B frag
typedef __attribute__((ext_vector_type(4))) float f32x4;
typedef __attribute__((ext_vector_type(16))) float f32x16;   // 32x32 MFMA C/D
typedef __attribute__((ext_vector_type(4))) int int4v;
typedef __attribute__((ext_vector_type(4))) unsigned short ushort4v;

#define MFMA16(A,B,C) __builtin_amdgcn_mfma_f32_16x16x32_bf16(A,B,C,0,0,0)
#define MFMA32(A,B,C) __builtin_amdgcn_mfma_f32_32x32x16_bf16(A,B,C,0,0,0)

#define FENCE() asm volatile("" ::: "memory")
#define SBAR()  do { FENCE(); __builtin_amdgcn_s_barrier(); FENCE(); } while (0)
#define WAITVN(N) asm volatile("s_waitcnt vmcnt(" #N ")" ::: "memory")
#define LGKM0() asm volatile("s_waitcnt lgkmcnt(0)" ::: "memory")

// async global->LDS, 16B per lane. LDS dest = wave-uniform base + lane*16.
static __device__ __forceinline__ void g2lds16(const void* g, void* l) {
  __builtin_amdgcn_global_load_lds(
      (__attribute__((address_space(1))) void*)(g),
      (__attribute__((address_space(3))) void*)(l), 16, 0, 0);
}

// swizzled chunk index within a [rows][64 bf16] LDS tile (chunks = 8 bf16 = 16B)
static __device__ __forceinline__ int swz8(int row, int kc) {
  return row * 8 + (kc ^ (row & 7));
}

static __device__ __forceinline__ unsigned short f2bf_bits(float f) {
  bf16 t = __float2bfloat16(f); unsigned short u; __builtin_memcpy(&u, &t, 2); return u;
}
static __device__ __forceinline__ unsigned short f2h_bits(float f) {
  __half t = __float2half(f); unsigned short u; __builtin_memcpy(&u, &t, 2); return u;
}

// ---------------- merged preprocessing ----------------
template<bool HALFOUT>
static __device__ __forceinline__ void tileT(const float* __restrict__ in,
                                             unsigned short* __restrict__ out,
                                             int R, int C, int tr, int tc, int tid,
                                             float (*tls)[65]) {
  const int rr0 = tid >> 4, c4 = tid & 15;
  #pragma unroll
  for (int rr = 0; rr < 4; ++rr) {
    int r = rr0 + rr * 16;
    float4 v = *(const float4*)(in + (size_t)(tr * 64 + r) * C + tc * 64 + c4 * 4);
    tls[r][c4 * 4 + 0] = v.x; tls[r][c4 * 4 + 1] = v.y;
    tls[r][c4 * 4 + 2] = v.z; tls[r][c4 * 4 + 3] = v.w;
  }
  __syncthreads();
  #pragma unroll
  for (int rr = 0; rr < 4; ++rr) {
    int r2 = rr0 + rr * 16;
    ushort4v o;
    #pragma unroll
    for (int k = 0; k < 4; ++k) {
      float f = tls[c4 * 4 + k][r2];
      o[k] = HALFOUT ? f2h_bits(f) : f2bf_bits(f);
    }
    *(ushort4v*)(out + (size_t)(tc * 64 + r2) * R + tr * 64 + c4 * 4) = o;
  }
}

__global__ __launch_bounds__(256)
void k_prep(const float* __restrict__ x, bf16* __restrict__ xb,
            const float* __restrict__ wqkv, unsigned short* __restrict__ wqkvT,
            const float* __restrict__ wout, unsigned short* __restrict__ woutT,
            const float* __restrict__ mask, unsigned short* __restrict__ maskT) {
  __shared__ float tls[64][65];
  const int bid = blockIdx.x, tid = threadIdx.x;
  if (bid < 768) {                       // x fp32 -> bf16: 786432 float4s, 4 per thread
    #pragma unroll
    for (int j = 0; j < 4; ++j) {
      int i = bid * 1024 + j * 256 + tid;
      float4 v = ((const float4*)x)[i];
      bf16* po = xb + (size_t)i * 4;
      po[0] = __float2bfloat16(v.x); po[1] = __float2bfloat16(v.y);
      po[2] = __float2bfloat16(v.z); po[3] = __float2bfloat16(v.w);
    }
  } else if (bid < 876) {                // wqkv [384][1152] -> [1152][384] bf16
    int tt = bid - 768; tileT<false>(wqkv, wqkvT, 384, 1152, tt / 18, tt % 18, tid, tls);
  } else if (bid < 912) {                // wout [384][384] -> [384][384]T bf16
    int tt = bid - 876; tileT<false>(wout, woutT, 384, 384, tt / 6, tt % 6, tid, tls);
  } else {                               // mask [1024][1024] -> maskT fp16
    int tt = bid - 912; tileT<true>(mask, maskT, 1024, 1024, tt / 16, tt % 16, tid, tls);
  }
}

// ---------------- qkv GEMM: BM=128, BN=96, BK=64 -> grid 64x12 = 768 = 3 blocks/CU ----------------
// Single-buffered m97 structure (R13 proven config). 4 waves (2x2): wave owns
// 64x48 (4x3 16-frags). N-tile boundary lands exactly at col 768:
// by<8 => q/k (relu+eps), by>=8 => v (transposed write).
__global__ __launch_bounds__(256, 3)
void k_gemm_qkv(const bf16* __restrict__ A, const bf16* __restrict__ BT,
                bf16* __restrict__ Cb, bf16* __restrict__ vT)
{
  __shared__ __align__(16) bf16 As[128 * 64];   // 16 KB
  __shared__ __align__(16) bf16 Bs[96 * 64];    // 12 KB
  const int tid = threadIdx.x;
  const int wave = tid >> 6, lane = tid & 63;
  const int lhi = lane >> 4, llo = lane & 15;
  const int wr = wave >> 1, wc = wave & 1;
  const int mBase = blockIdx.x * 128, nBase = blockIdx.y * 96;
  const int K = 384, N = 1152;

  f32x4 acc[4][3] = {};

  for (int kt = 0; kt < K; kt += 64) {
    __syncthreads();
    #pragma unroll
    for (int i = 0; i < 4; ++i) {               // A: 1024 chunks
      int c = i * 256 + tid;
      int row = c >> 3;
      int kc = (c & 7) ^ (row & 7);
      g2lds16(A + (size_t)(mBase + row) * K + kt + kc * 8, As + (c & ~63) * 8);
    }
    #pragma unroll
    for (int i = 0; i < 3; ++i) {               // B: 768 chunks
      int c = i * 256 + tid;
      int row = c >> 3;
      int kc = (c & 7) ^ (row & 7);
      g2lds16(BT + (size_t)(nBase + row) * K + kt + kc * 8, Bs + (c & ~63) * 8);
    }
    __syncthreads();
    for (int kk = 0; kk < 2; ++kk) {
      const int kc = kk * 4 + lhi;
      short8 a[4], b[3];
      #pragma unroll
      for (int mi = 0; mi < 4; ++mi)
        a[mi] = *(const short8*)(As + swz8(wr * 64 + mi * 16 + llo, kc) * 8);
      #pragma unroll
      for (int ni = 0; ni < 3; ++ni)
        b[ni] = *(const short8*)(Bs + swz8(wc * 48 + ni * 16 + llo, kc) * 8);
      #pragma unroll
      for (int mi = 0; mi < 4; ++mi)
        #pragma unroll
        for (int ni = 0; ni < 3; ++ni)
          acc[mi][ni] = MFMA16(a[mi], b[ni], acc[mi][ni]);
    }
  }

  const bool isV = (nBase >= 768);
  #pragma unroll
  for (int mi = 0; mi < 4; ++mi)
    #pragma unroll
    for (int ni = 0; ni < 3; ++ni) {
      const int colbase = nBase + wc * 48 + ni * 16;
      if (!isV) {
        #pragma unroll
        for (int j = 0; j < 4; ++j) {
          int row = mBase + wr * 64 + mi * 16 + lhi * 4 + j;
          int col = colbase + llo;
          float v = fmaxf(acc[mi][ni][j], 0.f) + 1e-6f;   // relu+eps on q,k
          Cb[(size_t)row * N + col] = __float2bfloat16(v);
        }
      } else {                                             // v-section -> vT[bh][d][n]
        int col = colbase + llo;
        int dall = col - 768, hh = dall >> 6, dd = dall & 63;
        int rowg = mBase + wr * 64 + mi * 16 + lhi * 4;
        int bb = rowg >> 10, nloc = rowg & 1023;
        ushort4v pk;
        #pragma unroll
        for (int j = 0; j < 4; ++j) pk[j] = f2bf_bits(acc[mi][ni][j]);
        *(ushort4v*)((unsigned short*)vT + (((size_t)bb * 6 + hh) * 64 + dd) * 1024 + nloc) = pk;
      }
    }
}

// ---------------- fused masked linear attention (R13/R17, measured-best config) ----------------
// 3-buffer LDS rotation -> ONE barrier per iteration; counted WAITVN(4);
// mask register-double-buffered, prefetched 1 iter ahead (manual 2x unroll).
__global__ __launch_bounds__(256, 3)
void k_attn(const bf16* __restrict__ qkv,     // [8192][1152] (q,k sections)
            const bf16* __restrict__ vT,      // [48][64][1024]
            const __half* __restrict__ maskT, // [1024 m][1024 q] fp16
            bf16* __restrict__ out)           // [8192][384]
{
  __shared__ __align__(16) char smem[49664];
  bf16* KsB = (bf16*)smem;                    // 3 x [64*64] (24 KB)
  bf16* VsB = KsB + 3 * 4096;                 // 3 x [64*64] (24 KB)
  float* OredF = (float*)smem;                // [2][32][65] = 16640 B (alias, post-loop)
  float* zredF = (float*)(smem + 49152);      // [2][2][32]  = 512 B

  const int bid = blockIdx.x;
  const int bh = bid % 48, qt = bid / 48;
  const int b = bh / 6, h = bh - b * 6;
  const int tid = threadIdx.x, wave = tid >> 6, lane = tid & 63;
  const int lq = lane & 31, lh = lane >> 5;
  const int wq = wave & 1, wm = wave >> 1;
  const size_t row0 = (size_t)b * 1024;
  const int qglob = qt * 64 + wq * 32 + lq;

  auto stageKV = [&](int mt, int buf) {
    #pragma unroll
    for (int i = 0; i < 2; ++i) {
      int c = (wave * 2 + i) * 64 + lane;
      int row = c >> 3;
      int kc = (c & 7) ^ (row & 7);
      g2lds16(qkv + (row0 + mt * 64 + row) * 1152 + 384 + h * 64 + kc * 8,
              KsB + buf * 4096 + (c & ~63) * 8);
      g2lds16(vT + ((size_t)bh * 64 + row) * 1024 + mt * 64 + kc * 8,
              VsB + buf * 4096 + (c & ~63) * 8);
    }
  };
  auto loadMask = [&](int mt, __half (&mv)[16]) {
    const int mrow0 = mt * 64 + wm * 32 + 4 * lh;
    #pragma unroll
    for (int g = 0; g < 4; ++g)
      #pragma unroll
      for (int j = 0; j < 4; ++j)
        mv[g * 4 + j] = maskT[(size_t)(mrow0 + 8 * g + j) * 1024 + qglob];
  };

  // Q fragments (B-operand): lane holds Q[qglob][ks*16 + lh*8 + e]
  short8 bq[4];
  {
    const bf16* qp = qkv + (row0 + qglob) * 1152 + h * 64 + lh * 8;
    #pragma unroll
    for (int ks = 0; ks < 4; ++ks) bq[ks] = *(const short8*)(qp + ks * 16);
  }

  f32x16 accO[2] = {};   // [db] : O[q 32][d 32] quadrants
  float zl = 0.f;

  __half mvA[16], mvB[16];
  stageKV(0, 0);
  loadMask(0, mvA);      // prologue mask; retired by iter 0's WAITVN(4)

  auto iter = [&](int t, __half (&mvUse)[16], __half (&mvPre)[16]) {
    const int bc = t % 3;
    const bf16* Kc = KsB + bc * 4096;
    const bf16* Vc = VsB + bc * 4096;

    if (t < 15) {
      stageKV(t + 1, (t + 1) % 3);
      WAITVN(4);           // retires stage(t) (+mask(t)); stage(t+1) stays in flight
    } else {
      WAITVN(0);
    }
    LGKM0();               // own LDS reads retired
    SBAR();                // buf[bc] fully populated across waves

    if (t < 15) loadMask(t + 1, mvPre);   // prefetch; lands during this iter

    // S^T[32m][32q] = K . Q^T over d=64 (4 k-steps)
    f32x16 st = {};
    #pragma unroll
    for (int ks = 0; ks < 4; ++ks) {
      int row = wm * 32 + lq;
      int cc = (ks * 2 + lh) ^ (row & 7);
      short8 af = *(const short8*)(Kc + (row * 8 + cc) * 8);
      st = MFMA32(af, bq[ks], st);
    }

    // P = S*mask (f32), z partial, pack to bf16 PA-frags in registers
    float p[16];
    {
      float zp = 0.f;
      #pragma unroll
      for (int r = 0; r < 16; ++r) {
        p[r] = st[r] * __half2float(mvUse[r]);
        zp += p[r];
      }
      zl += zp;
    }
    int u[4][2];
    #pragma unroll
    for (int g = 0; g < 4; ++g)
      #pragma unroll
      for (int c = 0; c < 2; ++c)
        asm("v_cvt_pk_bf16_f32 %0, %1, %2"
            : "=v"(u[g][c]) : "v"(p[4 * g + 2 * c]), "v"(p[4 * g + 2 * c + 1]));

    short8 pa[2];
    #pragma unroll
    for (int ks = 0; ks < 2; ++ks) {
      int A0 = u[2 * ks][0], A0b = u[2 * ks][1];
      int A1 = u[2 * ks + 1][0], A1b = u[2 * ks + 1][1];
      int x0 = __shfl_xor(A0, 32), x1 = __shfl_xor(A0b, 32);
      int y0 = __shfl_xor(A1, 32), y1 = __shfl_xor(A1b, 32);
      int4v iv;
      iv.x = lh ? y0 : A0;    // e 0,1
      iv.y = lh ? y1 : A0b;   // e 2,3
      iv.z = lh ? A1 : x0;    // e 4,5
      iv.w = lh ? A1b : x1;   // e 6,7
      pa[ks] = *(short8*)&iv;
    }

    // O[q][d] += P . V^T  (b-frag rows = V^T[d][m])
    #pragma unroll
    for (int db = 0; db < 2; ++db)
      #pragma unroll
      for (int ks = 0; ks < 2; ++ks) {
        int row = db * 32 + lq;
        int cc = (wm * 4 + ks * 2 + lh) ^ (row & 7);
        short8 vb = *(const short8*)(Vc + (row * 8 + cc) * 8);
        accO[db] = MFMA32(pa[ks], vb, accO[db]);
      }
  };

  #pragma unroll 1
  for (int mt2 = 0; mt2 < 8; ++mt2) {
    iter(2 * mt2,     mvA, mvB);
    iter(2 * mt2 + 1, mvB, mvA);
  }
  __syncthreads();   // all waves done with K/V buffers before Ored alias writes

  // cross-wave (wm) reduction of O and z, scale, store
  zl += __shfl_xor(zl, 32);
  zredF[(wq * 2 + wm) * 32 + lq] = zl;
  if (wm == 1) {
    #pragma unroll
    for (int db = 0; db < 2; ++db)
      #pragma unroll
      for (int r = 0; r < 16; ++r) {
        int q = (r & 3) + 8 * (r >> 2) + 4 * lh;
        OredF[(wq * 32 + q) * 65 + db * 32 + lq] = accO[db][r];
      }
  }
  __syncthreads();
  if (wm == 0) {
    #pragma unroll
    for (int r = 0; r < 16; ++r) {
      int q = (r & 3) + 8 * (r >> 2) + 4 * lh;
      float zt = zredF[wq * 2 * 32 + q] + zredF[(wq * 2 + 1) * 32 + q];
      float zi = 1.f / (zt + 1e-6f);
      int n = qt * 64 + wq * 32 + q;
      size_t orow = (row0 + n) * 384 + h * 64;
      #pragma unroll
      for (int db = 0; db < 2; ++db) {
        float val = (accO[db][r] + OredF[(wq * 32 + q) * 65 + db * 32 + lq]) * zi;
        out[orow + db * 32 + lq] = __float2bfloat16(val);
      }
    }
  }
}

// ---------------- out-projection GEMM: 64x64 tile, 32x32 MFMA ----------------
__global__ __launch_bounds__(256, 3)
void k_gemm_out(const bf16* __restrict__ A, const bf16* __restrict__ BT,
                float* __restrict__ Cf, const float* __restrict__ bias)
{
  __shared__ __align__(16) bf16 As[64 * 64];
  __shared__ __align__(16) bf16 Bs[64 * 64];
  const int tid = threadIdx.x;
  const int wave = tid >> 6, lane = tid & 63;
  const int lq = lane & 31, lh = lane >> 5;
  const int wr = wave >> 1, wc = wave & 1;
  const int mBase = blockIdx.x * 64, nBase = blockIdx.y * 64;
  const int N = 384, K = 384;

  f32x16 acc = {};
  for (int kt = 0; kt < K; kt += 64) {
    __syncthreads();
    #pragma unroll
    for (int i = 0; i < 2; ++i) {
      int c = (wave * 2 + i) * 64 + lane;
      int row = c >> 3;
      int kc = (c & 7) ^ (row & 7);
      g2lds16(A  + (size_t)(mBase + row) * K + kt + kc * 8, As + (c & ~63) * 8);
      g2lds16(BT + (size_t)(nBase + row) * K + kt + kc * 8, Bs + (c & ~63) * 8);
    }
    __syncthreads();
    #pragma unroll
    for (int ks = 0; ks < 4; ++ks) {
      int ra = wr * 32 + lq, rb = wc * 32 + lq;
      short8 a = *(const short8*)(As + (ra * 8 + ((ks * 2 + lh) ^ (ra & 7))) * 8);
      short8 b = *(const short8*)(Bs + (rb * 8 + ((ks * 2 + lh) ^ (rb & 7))) * 8);
      acc = MFMA32(a, b, acc);
    }
  }
  #pragma unroll
  for (int r = 0; r < 16; ++r) {
    int row = mBase + wr * 32 + (r & 3) + 8 * (r >> 2) + 4 * lh;
    int col = nBase + wc * 32 + lq;
    Cf[(size_t)row * N + col] = acc[r] + bias[col];
  }
}

extern "C" void kernel_launch(void* const* d_in, const int* in_sizes, int n_in,
                              void* d_out, int out_size, void* d_ws, size_t ws_size,
                              hipStream_t stream) {
  (void)in_sizes; (void)n_in; (void)out_size; (void)ws_size;
  const float* x    = (const float*)d_in[0];   // [8,1024,384]
  const float* wqkv = (const float*)d_in[1];   // [384,1152]
  const float* wout = (const float*)d_in[2];   // [384,384]
  const float* bout = (const float*)d_in[3];   // [384]
  const float* mask = (const float*)d_in[4];   // [1024,1024]
  float* outp = (float*)d_out;

  char* ws = (char*)d_ws;
  bf16*  xb    = (bf16*)(ws);                  // 8192*384
  bf16*  wqkvT = (bf16*)(ws + 6291456);        // 1152*384
  bf16*  woutT = (bf16*)(ws + 7176192);        // 384*384
  bf16*  qkvb  = (bf16*)(ws + 7471104);        // 8192*1152 (q,k only)
  bf16*  vTb   = (bf16*)(ws + 26345472);       // 48*64*1024
  bf16*  ab    = (bf16*)(ws + 32636928);       // 8192*384
  __half* maskT = (__half*)(ws + 38928384);    // 1024*1024 fp16 (transposed)

  k_prep<<<dim3(1168), dim3(256), 0, stream>>>(
      x, xb, wqkv, (unsigned short*)wqkvT, wout, (unsigned short*)woutT,
      mask, (unsigned short*)maskT);

  k_gemm_qkv<<<dim3(64, 12), dim3(256), 0, stream>>>(xb, wqkvT, qkvb, vTb);
  k_attn<<<dim3(768), dim3(256), 0, stream>>>(qkvb, vTb, maskT, ab);
  k_gemm_out<<<dim3(128, 6), dim3(256), 0, stream>>>(ab, woutT, outp, bout);
}